// Round 7
// baseline (207.211 us; speedup 1.0000x reference)
//
#include <hip/hip_runtime.h>
#include <hip/hip_bf16.h>

// Problem constants (B=32, H=W=96, D=5, R=5, A=10, K=2, FA=4, T=7)
#define HW 9216
#define NB 32
#define NPOS (NB*HW)   // 294912

// ---- float <-> order-preserving unsigned encoding for atomic min/max ----
__device__ inline unsigned fenc(float f){
    unsigned u = __float_as_uint(f);
    return (u & 0x80000000u) ? ~u : (u | 0x80000000u);
}
__device__ inline float fdec(unsigned u){
    return __uint_as_float((u & 0x80000000u) ? (u & 0x7fffffffu) : ~u);
}

// ---------------- Kernel 1: le = avgpool3x3(mf)+mf, global per-channel min/max ----------------
__global__ __launch_bounds__(256) void k_le(const float* __restrict__ mf,
                                            float* __restrict__ le,
                                            unsigned* __restrict__ mm /*[4]: max0,max1,min0,min1*/){
    int n = blockIdx.x * 256 + threadIdx.x;        // n < NB*2*HW
    int p = n % HW;
    int bc = n / HW;
    int c = bc & 1;
    int h = p / 96, w = p % 96;
    const float* plane = mf + (size_t)bc * HW;
    float s = 0.f;
    #pragma unroll
    for(int dy=-1; dy<=1; ++dy){
        int y = h + dy;
        if((unsigned)y < 96u){
            #pragma unroll
            for(int dx=-1; dx<=1; ++dx){
                int x = w + dx;
                if((unsigned)x < 96u) s += plane[y*96 + x];
            }
        }
    }
    float v = s * (1.0f/9.0f) + plane[p];
    le[n] = v;

    float mx = v, mn = v;
    #pragma unroll
    for(int o=32; o; o>>=1){
        mx = fmaxf(mx, __shfl_xor(mx, o));
        mn = fminf(mn, __shfl_xor(mn, o));
    }
    __shared__ float smx[4], smn[4];
    int wv = threadIdx.x >> 6;
    if((threadIdx.x & 63) == 0){ smx[wv] = mx; smn[wv] = mn; }
    __syncthreads();
    if(threadIdx.x == 0){
        for(int i=1;i<4;i++){ mx = fmaxf(mx, smx[i]); mn = fminf(mn, smn[i]); }
        atomicMax(&mm[c],     fenc(mx));
        atomicMin(&mm[2 + c], fenc(mn));
    }
}

// ---------------- Kernel 2: df = LeakyReLU(conv3x3([norm(le), uf], Wd) + bd) ----------------
__global__ __launch_bounds__(256) void k_dirconv(const float* __restrict__ uf,
                                                 const float* __restrict__ le,
                                                 const unsigned* __restrict__ mm,
                                                 const float* __restrict__ Wdw,
                                                 const float* __restrict__ bdw,
                                                 float* __restrict__ df){
    __shared__ float sW[180];
    __shared__ float sb[4];
    for(int i=threadIdx.x; i<180; i+=256) sW[i] = Wdw[i];
    if(threadIdx.x < 4) sb[threadIdx.x] = bdw[threadIdx.x];
    __syncthreads();

    int n = blockIdx.x * 256 + threadIdx.x;        // n < NB*HW
    int b = n / HW, p = n % HW;
    int h = p / 96, w = p % 96;

    float mx0 = fdec(mm[0]), mx1 = fdec(mm[1]);
    float mn0 = fdec(mm[2]), mn1 = fdec(mm[3]);
    float sc0 = 2.f / (mx0 - mn0), sc1 = 2.f / (mx1 - mn1);
    float of0 = -1.f - mn0 * sc0,  of1 = -1.f - mn1 * sc1;

    float acc0 = sb[0], acc1 = sb[1], acc2 = sb[2], acc3 = sb[3];
    #pragma unroll
    for(int i=0;i<5;i++){
        #pragma unroll
        for(int ky=0; ky<3; ky++){
            int y = h + ky - 1;
            if((unsigned)y >= 96u) continue;
            #pragma unroll
            for(int kx=0; kx<3; kx++){
                int x = w + kx - 1;
                if((unsigned)x >= 96u) continue;
                float v;
                if(i < 2) v = le[((size_t)b*2 + i)*HW + y*96 + x] * (i ? sc1 : sc0) + (i ? of1 : of0);
                else      v = uf[((size_t)b*3 + (i-2))*HW + y*96 + x];
                acc0 += v * sW[((0*5+i)*3+ky)*3+kx];
                acc1 += v * sW[((1*5+i)*3+ky)*3+kx];
                acc2 += v * sW[((2*5+i)*3+ky)*3+kx];
                acc3 += v * sW[((3*5+i)*3+ky)*3+kx];
            }
        }
    }
    size_t ob = ((size_t)b*4)*HW + p;
    df[ob + 0*HW] = acc0 > 0.f ? acc0 : 0.01f*acc0;
    df[ob + 1*HW] = acc1 > 0.f ? acc1 : 0.01f*acc1;
    df[ob + 2*HW] = acc2 > 0.f ? acc2 : 0.01f*acc2;
    df[ob + 3*HW] = acc3 > 0.f ? acc3 : 0.01f*acc3;
}

// ---------------- Kernel 3: flat contiguous stream -> word!=0 bit planes ----------------
// Concatenated chunk space (1 chunk = 4096 words = 256 ushorts of bits):
//   T:[0,18000) M:[18000,18720) P:[18720,22320) D:[22320,22464)
//   S:[22464,22608) R:[22608,22752) N:[22752,22824) F:[22824,23112)
#define NCHUNK 23112
__global__ __launch_bounds__(256) void k_bits(
    const int* __restrict__ vaT, const int* __restrict__ vaM, const int* __restrict__ vaP,
    const int* __restrict__ vaD, const int* __restrict__ vaS, const int* __restrict__ vaR,
    const int* __restrict__ vaN, const int* __restrict__ vaF,
    unsigned short* __restrict__ bits)
{
    for(int chunk = blockIdx.x; chunk < NCHUNK; chunk += gridDim.x){
        const int* src; size_t u16;
        if(chunk < 18000){      src = vaT + (size_t)chunk*4096;        u16 = (size_t)chunk*256; }
        else if(chunk < 18720){ int c = chunk-18000; src = vaM + (size_t)c*4096; u16 = 4608000 + (size_t)c*256; }
        else if(chunk < 22320){ int c = chunk-18720; src = vaP + (size_t)c*4096; u16 = 4792320 + (size_t)c*256; }
        else if(chunk < 22464){ int c = chunk-22320; src = vaD + (size_t)c*4096; u16 = 5713920 + (size_t)c*256; }
        else if(chunk < 22608){ int c = chunk-22464; src = vaS + (size_t)c*4096; u16 = 5750784 + (size_t)c*256; }
        else if(chunk < 22752){ int c = chunk-22608; src = vaR + (size_t)c*4096; u16 = 5787648 + (size_t)c*256; }
        else if(chunk < 22824){ int c = chunk-22752; src = vaN + (size_t)c*4096; u16 = 5824512 + (size_t)c*256; }
        else                  { int c = chunk-22824; src = vaF + (size_t)c*4096; u16 = 5842944 + (size_t)c*256; }

        const int4* s4 = (const int4*)src + (size_t)threadIdx.x*4;
        int4 v0 = s4[0], v1 = s4[1], v2 = s4[2], v3 = s4[3];
        unsigned m =
            ((unsigned)(v0.x!=0)    ) | ((unsigned)(v0.y!=0)<<1 ) | ((unsigned)(v0.z!=0)<<2 ) | ((unsigned)(v0.w!=0)<<3 ) |
            ((unsigned)(v1.x!=0)<<4 ) | ((unsigned)(v1.y!=0)<<5 ) | ((unsigned)(v1.z!=0)<<6 ) | ((unsigned)(v1.w!=0)<<7 ) |
            ((unsigned)(v2.x!=0)<<8 ) | ((unsigned)(v2.y!=0)<<9 ) | ((unsigned)(v2.z!=0)<<10) | ((unsigned)(v2.w!=0)<<11) |
            ((unsigned)(v3.x!=0)<<12) | ((unsigned)(v3.y!=0)<<13) | ((unsigned)(v3.z!=0)<<14) | ((unsigned)(v3.w!=0)<<15);
        bits[u16 + threadIdx.x] = (unsigned short)m;
    }
}

// ---------------- Kernel 4: reduce bit planes -> per-position tvm/pkd words ----------------
// byte offsets within bits region: bT=0 bM=9216000 bP=9584640 bD=11427840
//   bS=11501568 bR=11575296 bN=11649024 bF=11685888 ; plane byte stride = HW/8 = 1152
__global__ __launch_bounds__(256) void k_masks2(const unsigned char* __restrict__ B,
                                                unsigned* __restrict__ tvm,
                                                unsigned* __restrict__ pkd)
{
    int t = blockIdx.x * 256 + threadIdx.x;        // < NPOS/8 = 36864
    int b  = t / (HW/8);
    int p8 = t - b*(HW/8);

    unsigned tvw[8] = {0,0,0,0,0,0,0,0};
    #pragma unroll 5
    for(int g=0; g<25; g++){
        unsigned acc = 0;
        #pragma unroll
        for(int a=0; a<10; a++)
            acc |= B[0 + ((size_t)b*250 + g*10 + a)*1152 + p8];
        #pragma unroll
        for(int j=0;j<8;j++) tvw[j] |= ((acc>>j)&1u) << g;
    }

    unsigned pkw[8] = {0,0,0,0,0,0,0,0};
    #pragma unroll
    for(int d=0; d<5; d++){
        unsigned acc = B[9216000 + ((size_t)b*10 + 2*d  )*1152 + p8]
                     | B[9216000 + ((size_t)b*10 + 2*d+1)*1152 + p8];
        #pragma unroll
        for(int j=0;j<8;j++) pkw[j] |= ((acc>>j)&1u) << d;
    }
    #pragma unroll 5
    for(int r=0; r<5; r++){
        unsigned acc = 0;
        #pragma unroll
        for(int a=0; a<10; a++)
            acc |= B[9584640 + ((size_t)b*50 + r*10 + a)*1152 + p8];
        #pragma unroll
        for(int j=0;j<8;j++) pkw[j] |= ((acc>>j)&1u) << (5+r);
    }
    {
        unsigned d0 = B[11427840 + ((size_t)b*2+0)*1152 + p8];
        unsigned d1 = B[11427840 + ((size_t)b*2+1)*1152 + p8];
        unsigned sd = B[11501568 + ((size_t)b*2+0)*1152 + p8]
                    | B[11501568 + ((size_t)b*2+1)*1152 + p8];
        unsigned rc = B[11575296 + ((size_t)b*2+0)*1152 + p8]
                    | B[11575296 + ((size_t)b*2+1)*1152 + p8];
        unsigned dn = B[11649024 + (size_t)b*1152 + p8];
        #pragma unroll
        for(int j=0;j<8;j++){
            pkw[j] |= (((d0>>j)&1u)<<10) | (((d1>>j)&1u)<<11)
                    | (((sd>>j)&1u)<<12) | (((rc>>j)&1u)<<13) | (((dn>>j)&1u)<<14);
        }
        #pragma unroll
        for(int c=0;c<4;c++){
            unsigned fv = B[11685888 + ((size_t)b*4+c)*1152 + p8];
            #pragma unroll
            for(int j=0;j<8;j++) pkw[j] |= ((fv>>j)&1u) << (15+c);
        }
    }

    size_t q = (size_t)b*HW + (size_t)p8*8;
    *(uint4*)(tvm + q)     = make_uint4(tvw[0],tvw[1],tvw[2],tvw[3]);
    *(uint4*)(tvm + q + 4) = make_uint4(tvw[4],tvw[5],tvw[6],tvw[7]);
    *(uint4*)(pkd + q)     = make_uint4(pkw[0],pkw[1],pkw[2],pkw[3]);
    *(uint4*)(pkd + q + 4) = make_uint4(pkw[4],pkw[5],pkw[6],pkw[7]);
}

// ---- masked categorical: lp at argmax, argmax (first max), entropy over valid ----
template<int N>
__device__ __forceinline__ void mcat(const float* x, unsigned mask, float& lp, int& a, float& en){
    float ml[N];
    #pragma unroll
    for(int i=0;i<N;i++) ml[i] = ((mask >> i) & 1u) ? x[i] : -1e9f;
    float m = ml[0]; int am = 0;
    #pragma unroll
    for(int i=1;i<N;i++) if(ml[i] > m){ m = ml[i]; am = i; }
    float S = 0.f, T = 0.f;
    #pragma unroll
    for(int i=0;i<N;i++){
        float d = ml[i] - m;
        float e = expf(d);         // invalid entries: exp(-1e9-m) == 0 exactly
        S += e; T += e * d;
    }
    float lS = logf(S);
    lp = -lS;                      // ml[argmax] == m  =>  lp = m - (m + log S)
    a  = am;
    en = lS - T / S;               // == -sum_valid p*lp  (exact when >=1 valid; unused otherwise)
}

// ---------------- Kernel 5: per-position heads (compact masks in) ----------------
__global__ __launch_bounds__(256) void k_heads(
    const float* __restrict__ mf, const float* __restrict__ uf, const float* __restrict__ ff,
    const int* __restrict__ loc,
    const unsigned* __restrict__ tvm, const unsigned* __restrict__ pkd,
    const float* Wc, const float* bc, const float* Wf, const float* bf,
    const float* Wt, const float* bt, const float* Wmd, const float* bmd,
    const float* Wtd, const float* btd, const float* Wtr, const float* btr,
    const float* Wta, const float* bta, const float* Wpr, const float* bpr,
    const float* Wpa, const float* bpa, const float* Wra, const float* bra,
    const float* Wdr, const float* bdr,
    const float* __restrict__ df,
    float* __restrict__ crm, float* __restrict__ lpm, float* __restrict__ enm,
    int* __restrict__ idx, float* __restrict__ out)
{
    __shared__ float sw[336];
    {
        int t = threadIdx.x;
        #define CPW(off, src, n) for(int i=t;i<(n);i+=256) sw[(off)+i]=(src)[i];
        CPW(0,Wc,5)    CPW(5,bc,1)    CPW(6,Wf,24)   CPW(30,bf,4)
        CPW(34,Wt,35)  CPW(69,bt,7)   CPW(76,Wmd,20) CPW(96,bmd,5)
        CPW(101,Wtd,20) CPW(121,btd,5) CPW(126,Wtr,20) CPW(146,btr,5)
        CPW(151,Wta,40) CPW(191,bta,10) CPW(201,Wpr,20) CPW(221,bpr,5)
        CPW(226,Wpa,40) CPW(266,bpa,10) CPW(276,Wra,40) CPW(316,bra,10)
        CPW(326,Wdr,8)  CPW(334,bdr,2)
        #undef CPW
    }
    __syncthreads();

    int n = blockIdx.x * 256 + threadIdx.x;        // n < NB*HW
    int b = n / HW, p = n % HW;
    size_t q = (size_t)b*HW + p;

    unsigned tv = tvm[q];
    unsigned pk = pkd[q];
    unsigned mvm  = pk & 31u;
    unsigned pkm  = (pk >> 5) & 31u;
    unsigned digm = (pk >> 10) & 3u;
    unsigned sd1  = (pk >> 12) & 1u;
    unsigned rc1  = (pk >> 13) & 1u;
    unsigned dn1  = (pk >> 14) & 1u;
    unsigned fam  = (pk >> 15) & 15u;

    unsigned uat = (mvm ? 1u:0u) | ((tv ? 1u:0u)<<1) | ((pkm ? 1u:0u)<<2) | ((digm ? 1u:0u)<<3)
                 | (sd1<<4) | (rc1<<5) | (dn1<<6);
    bool um = (uat != 0);

    // features
    float vf5[5];
    vf5[0] = mf[((size_t)b*2+0)*HW + p];
    vf5[1] = mf[((size_t)b*2+1)*HW + p];
    vf5[2] = uf[((size_t)b*3+0)*HW + p];
    vf5[3] = uf[((size_t)b*3+1)*HW + p];
    vf5[4] = uf[((size_t)b*3+2)*HW + p];
    float d4[4];
    #pragma unroll
    for(int o=0;o<4;o++) d4[o] = df[((size_t)b*4+o)*HW + p];
    float f6[6];
    #pragma unroll
    for(int j=0;j<6;j++) f6[j] = ff[((size_t)b*6+j)*HW + p];

    // critic
    float critic = sw[5];
    #pragma unroll
    for(int c=0;c<5;c++) critic += sw[c] * vf5[c];

    // factory masked argmax
    int fact = 0; float fb = -3e38f;
    #pragma unroll
    for(int j=0;j<4;j++){
        float lg = sw[30+j];
        #pragma unroll
        for(int c=0;c<6;c++) lg += sw[6 + j*6 + c] * f6[c];
        float mlv = ((fam >> j) & 1u) ? lg : -1e9f;
        if(mlv > fb){ fb = mlv; fact = j; }
    }

    // act-type head
    float tl[7];
    #pragma unroll
    for(int i=0;i<7;i++){
        float s = sw[69+i];
        #pragma unroll
        for(int c=0;c<5;c++) s += sw[34 + i*5 + c] * vf5[c];
        tl[i] = s;
    }
    float t_lp, t_en; int tt;
    mcat<7>(tl, uat, t_lp, tt, t_en);

    float hl[10];

    #pragma unroll
    for(int i=0;i<5;i++){ float s = sw[96+i];
        #pragma unroll
        for(int c=0;c<4;c++) s += sw[76 + i*4 + c] * d4[c]; hl[i]=s; }
    float lpmv, enmv; int mvdir; mcat<5>(hl, mvm, lpmv, mvdir, enmv);

    #pragma unroll
    for(int i=0;i<5;i++){ float s = sw[121+i];
        #pragma unroll
        for(int c=0;c<4;c++) s += sw[101 + i*4 + c] * d4[c]; hl[i]=s; }
    unsigned trd = 0;
    #pragma unroll
    for(int d=0; d<5; d++) trd |= (unsigned)(((tv >> (5*d)) & 31u) != 0) << d;
    float lptd, entd; int trdir; mcat<5>(hl, trd, lptd, trdir, entd);

    #pragma unroll
    for(int i=0;i<5;i++){ float s = sw[146+i];
        #pragma unroll
        for(int c=0;c<4;c++) s += sw[126 + i*4 + c] * d4[c]; hl[i]=s; }
    float lptr, entr; int trres; mcat<5>(hl, (tv >> (trdir*5)) & 31u, lptr, trres, entr);

    #pragma unroll
    for(int i=0;i<10;i++){ float s = sw[191+i];
        #pragma unroll
        for(int c=0;c<4;c++) s += sw[151 + i*4 + c] * d4[c]; hl[i]=s; }
    float lpta, enta; int tramt; mcat<10>(hl, 0x3FFu, lpta, tramt, enta);

    #pragma unroll
    for(int i=0;i<5;i++){ float s = sw[221+i];
        #pragma unroll
        for(int c=0;c<4;c++) s += sw[201 + i*4 + c] * d4[c]; hl[i]=s; }
    float lppr, enpr; int pkres; mcat<5>(hl, pkm, lppr, pkres, enpr);

    #pragma unroll
    for(int i=0;i<10;i++){ float s = sw[266+i];
        #pragma unroll
        for(int c=0;c<4;c++) s += sw[226 + i*4 + c] * d4[c]; hl[i]=s; }
    float lppa, enpa; int pkamt; mcat<10>(hl, 0x3FFu, lppa, pkamt, enpa);

    #pragma unroll
    for(int i=0;i<10;i++){ float s = sw[316+i];
        #pragma unroll
        for(int c=0;c<4;c++) s += sw[276 + i*4 + c] * d4[c]; hl[i]=s; }
    float lpra, enra; int rcamt; mcat<10>(hl, 0x3FFu, lpra, rcamt, enra);

    #pragma unroll
    for(int i=0;i<2;i++){ float s = sw[334+i];
        #pragma unroll
        for(int c=0;c<4;c++) s += sw[326 + i*4 + c] * d4[c]; hl[i]=s; }
    float lpdg, endg; int dgrep; mcat<2>(hl, digm, lpdg, dgrep, endg);

    float lps = 0.f, ens = 0.f; int dir = 0, res = 0, amt = 0, rep = 0;
    switch(tt){
        case 0: lps = lpmv;               ens = enmv;               dir = mvdir; break;
        case 1: lps = lptd + lptr + lpta; ens = entd + entr + enta; dir = trdir; res = trres; amt = tramt; break;
        case 2: lps = lppr + lppa;        ens = enpr + enpa;        res = pkres; amt = pkamt; break;
        case 3: lps = lpdg;               ens = endg;               rep = dgrep; break;
        case 5: lps = lpra;               ens = enra;               amt = rcamt; break;
        default: break;
    }
    float tot_lp = t_lp + lps;
    float tot_en = t_en + ens;

    crm[q] = critic;
    lpm[q] = tot_lp;
    enm[q] = tot_en;

    out[96000 + q] = (fam != 0) ? (float)fact : 0.f;
    size_t ub = 390912 + (size_t)b*6*HW + p;
    out[ub + 0*HW] = um ? (float)tt  : 0.f;
    out[ub + 1*HW] = um ? (float)dir : 0.f;
    out[ub + 2*HW] = um ? (float)res : 0.f;
    out[ub + 3*HW] = um ? (float)amt : 0.f;
    out[ub + 4*HW] = um ? (float)rep : 0.f;
    out[ub + 5*HW] = um ? 1.f : 0.f;

    // scatter winner: numpy last-write-wins == max linear position per (b,id)
    if(um){
        int id = loc[((size_t)b*2 + 1)*HW + p] + 10;
        if((unsigned)id < 1000u) atomicMax(&idx[b*1000 + id], p);
    }
}

// ---------------- Kernel 6: resolve [B,1000] scatters ----------------
__global__ __launch_bounds__(256) void k_gather(const int* __restrict__ idx,
                                                const float* __restrict__ crm,
                                                const float* __restrict__ lpm,
                                                const float* __restrict__ enm,
                                                float* __restrict__ out){
    int j = blockIdx.x * 256 + threadIdx.x;
    if(j >= 32000) return;
    int b = j / 1000;
    int pos = idx[j];
    float lp = 0.f, cv = 0.f, en = 0.f;
    if(pos >= 0){
        size_t q = (size_t)b*HW + pos;
        lp = lpm[q]; cv = crm[q]; en = enm[q];
    }
    out[j]          = lp;
    out[32000 + j]  = cv;
    out[64000 + j]  = en;
}

extern "C" void kernel_launch(void* const* d_in, const int* in_sizes, int n_in,
                              void* d_out, int out_size, void* d_ws, size_t ws_size,
                              hipStream_t stream) {
    const float* mf  = (const float*)d_in[1];
    const float* ffp = (const float*)d_in[2];
    const float* ufp = (const float*)d_in[3];
    const int*   loc = (const int*)d_in[4];
    const int* vaM = (const int*)d_in[5];
    const int* vaT = (const int*)d_in[6];
    const int* vaP = (const int*)d_in[7];
    const int* vaD = (const int*)d_in[8];
    const int* vaS = (const int*)d_in[9];
    const int* vaR = (const int*)d_in[10];
    const int* vaN = (const int*)d_in[11];
    const int* vaF = (const int*)d_in[12];
    const float *Wf=(const float*)d_in[13], *bf=(const float*)d_in[14];
    const float *Wc=(const float*)d_in[15], *bc=(const float*)d_in[16];
    const float *Wdw=(const float*)d_in[17], *bdw=(const float*)d_in[18];
    const float *Wt=(const float*)d_in[19], *bt=(const float*)d_in[20];
    const float *Wmd=(const float*)d_in[21], *bmd=(const float*)d_in[22];
    const float *Wtd=(const float*)d_in[23], *btd=(const float*)d_in[24];
    const float *Wtr=(const float*)d_in[25], *btr=(const float*)d_in[26];
    const float *Wta=(const float*)d_in[27], *bta=(const float*)d_in[28];
    const float *Wpr=(const float*)d_in[29], *bpr=(const float*)d_in[30];
    const float *Wpa=(const float*)d_in[31], *bpa=(const float*)d_in[32];
    const float *Wra=(const float*)d_in[33], *bra=(const float*)d_in[34];
    const float *Wdr=(const float*)d_in[35], *bdr=(const float*)d_in[36];

    char* ws = (char*)d_ws;
    float* le  = (float*)(ws + 0);                 // 32*2*9216*4  = 2,359,296
    float* df  = (float*)(ws + 2359296);           // 32*4*9216*4  = 4,718,592
    float* crm = (float*)(ws + 7077888);           // 32*9216*4    = 1,179,648
    float* lpm = (float*)(ws + 8257536);
    float* enm = (float*)(ws + 9437184);
    int*   idx = (int*)(ws + 10616832);            // 32*1000*4    = 128,000
    unsigned* mm = (unsigned*)(ws + 10744832);     // 16 B
    unsigned* tvm = (unsigned*)(ws + 10744848);    // NPOS*4 = 1,179,648
    unsigned* pkd = (unsigned*)(ws + 11924496);    // NPOS*4
    unsigned short* bits = (unsigned short*)(ws + 16777216); // 11,833,344 B

    hipMemsetAsync(mm, 0x00, 8, stream);           // max accumulators -> encoded -inf floor
    hipMemsetAsync((char*)mm + 8, 0xFF, 8, stream);// min accumulators -> encoded +inf ceil
    hipMemsetAsync(idx, 0xFF, 128000, stream);     // scatter winners -> -1

    k_bits<<<dim3(2304), dim3(256), 0, stream>>>(vaT, vaM, vaP, vaD, vaS, vaR, vaN, vaF, bits);
    k_le<<<dim3(2304), dim3(256), 0, stream>>>(mf, le, mm);
    k_dirconv<<<dim3(1152), dim3(256), 0, stream>>>(ufp, le, mm, Wdw, bdw, df);
    k_masks2<<<dim3(144), dim3(256), 0, stream>>>((const unsigned char*)bits, tvm, pkd);
    k_heads<<<dim3(1152), dim3(256), 0, stream>>>(
        mf, ufp, ffp, loc, tvm, pkd,
        Wc, bc, Wf, bf, Wt, bt, Wmd, bmd, Wtd, btd, Wtr, btr,
        Wta, bta, Wpr, bpr, Wpa, bpa, Wra, bra, Wdr, bdr,
        df, crm, lpm, enm, idx, (float*)d_out);
    k_gather<<<dim3(125), dim3(256), 0, stream>>>(idx, crm, lpm, enm, (float*)d_out);
}

// Round 8
// 206.085 us; speedup vs baseline: 1.0055x; 1.0055x over previous
//
#include <hip/hip_runtime.h>
#include <hip/hip_bf16.h>

// Problem constants (B=32, H=W=96, D=5, R=5, A=10, K=2, FA=4, T=7)
#define HW 9216
#define NB 32
#define NPOS (NB*HW)   // 294912

// ---- float <-> order-preserving unsigned encoding for atomic min/max ----
__device__ inline unsigned fenc(float f){
    unsigned u = __float_as_uint(f);
    return (u & 0x80000000u) ? ~u : (u | 0x80000000u);
}
__device__ inline float fdec(unsigned u){
    return __uint_as_float((u & 0x80000000u) ? (u & 0x7fffffffu) : ~u);
}

// ---------------- Kernel 1: le = avgpool3x3(mf)+mf, global per-channel min/max ----------------
__global__ __launch_bounds__(256) void k_le(const float* __restrict__ mf,
                                            float* __restrict__ le,
                                            unsigned* __restrict__ mm /*[4]: max0,max1,min0,min1*/){
    int n = blockIdx.x * 256 + threadIdx.x;        // n < NB*2*HW
    int p = n % HW;
    int bc = n / HW;
    int c = bc & 1;
    int h = p / 96, w = p % 96;
    const float* plane = mf + (size_t)bc * HW;
    float s = 0.f;
    #pragma unroll
    for(int dy=-1; dy<=1; ++dy){
        int y = h + dy;
        if((unsigned)y < 96u){
            #pragma unroll
            for(int dx=-1; dx<=1; ++dx){
                int x = w + dx;
                if((unsigned)x < 96u) s += plane[y*96 + x];
            }
        }
    }
    float v = s * (1.0f/9.0f) + plane[p];
    le[n] = v;

    float mx = v, mn = v;
    #pragma unroll
    for(int o=32; o; o>>=1){
        mx = fmaxf(mx, __shfl_xor(mx, o));
        mn = fminf(mn, __shfl_xor(mn, o));
    }
    __shared__ float smx[4], smn[4];
    int wv = threadIdx.x >> 6;
    if((threadIdx.x & 63) == 0){ smx[wv] = mx; smn[wv] = mn; }
    __syncthreads();
    if(threadIdx.x == 0){
        for(int i=1;i<4;i++){ mx = fmaxf(mx, smx[i]); mn = fminf(mn, smn[i]); }
        atomicMax(&mm[c],     fenc(mx));
        atomicMin(&mm[2 + c], fenc(mn));
    }
}

// ---------------- Kernel 2: df = LeakyReLU(conv3x3([norm(le), uf], Wd) + bd) ----------------
__global__ __launch_bounds__(256) void k_dirconv(const float* __restrict__ uf,
                                                 const float* __restrict__ le,
                                                 const unsigned* __restrict__ mm,
                                                 const float* __restrict__ Wdw,
                                                 const float* __restrict__ bdw,
                                                 float* __restrict__ df){
    __shared__ float sW[180];
    __shared__ float sb[4];
    for(int i=threadIdx.x; i<180; i+=256) sW[i] = Wdw[i];
    if(threadIdx.x < 4) sb[threadIdx.x] = bdw[threadIdx.x];
    __syncthreads();

    int n = blockIdx.x * 256 + threadIdx.x;        // n < NB*HW
    int b = n / HW, p = n % HW;
    int h = p / 96, w = p % 96;

    float mx0 = fdec(mm[0]), mx1 = fdec(mm[1]);
    float mn0 = fdec(mm[2]), mn1 = fdec(mm[3]);
    float sc0 = 2.f / (mx0 - mn0), sc1 = 2.f / (mx1 - mn1);
    float of0 = -1.f - mn0 * sc0,  of1 = -1.f - mn1 * sc1;

    float acc0 = sb[0], acc1 = sb[1], acc2 = sb[2], acc3 = sb[3];
    #pragma unroll
    for(int i=0;i<5;i++){
        #pragma unroll
        for(int ky=0; ky<3; ky++){
            int y = h + ky - 1;
            if((unsigned)y >= 96u) continue;
            #pragma unroll
            for(int kx=0; kx<3; kx++){
                int x = w + kx - 1;
                if((unsigned)x >= 96u) continue;
                float v;
                if(i < 2) v = le[((size_t)b*2 + i)*HW + y*96 + x] * (i ? sc1 : sc0) + (i ? of1 : of0);
                else      v = uf[((size_t)b*3 + (i-2))*HW + y*96 + x];
                acc0 += v * sW[((0*5+i)*3+ky)*3+kx];
                acc1 += v * sW[((1*5+i)*3+ky)*3+kx];
                acc2 += v * sW[((2*5+i)*3+ky)*3+kx];
                acc3 += v * sW[((3*5+i)*3+ky)*3+kx];
            }
        }
    }
    size_t ob = ((size_t)b*4)*HW + p;
    df[ob + 0*HW] = acc0 > 0.f ? acc0 : 0.01f*acc0;
    df[ob + 1*HW] = acc1 > 0.f ? acc1 : 0.01f*acc1;
    df[ob + 2*HW] = acc2 > 0.f ? acc2 : 0.01f*acc2;
    df[ob + 3*HW] = acc3 > 0.f ? acc3 : 0.01f*acc3;
}

// ---------------- Kernel 3: flat contiguous stream -> word!=0 bit planes ----------------
// Concatenated chunk space (1 chunk = 4096 words = 256 ushorts of bits):
//   T:[0,18000) M:[18000,18720) P:[18720,22320) D:[22320,22464)
//   S:[22464,22608) R:[22608,22752) N:[22752,22824) F:[22824,23112)
#define NCHUNK 23112
__global__ __launch_bounds__(256) void k_bits(
    const int* __restrict__ vaT, const int* __restrict__ vaM, const int* __restrict__ vaP,
    const int* __restrict__ vaD, const int* __restrict__ vaS, const int* __restrict__ vaR,
    const int* __restrict__ vaN, const int* __restrict__ vaF,
    unsigned short* __restrict__ bits)
{
    for(int chunk = blockIdx.x; chunk < NCHUNK; chunk += gridDim.x){
        const int* src; size_t u16;
        if(chunk < 18000){      src = vaT + (size_t)chunk*4096;        u16 = (size_t)chunk*256; }
        else if(chunk < 18720){ int c = chunk-18000; src = vaM + (size_t)c*4096; u16 = 4608000 + (size_t)c*256; }
        else if(chunk < 22320){ int c = chunk-18720; src = vaP + (size_t)c*4096; u16 = 4792320 + (size_t)c*256; }
        else if(chunk < 22464){ int c = chunk-22320; src = vaD + (size_t)c*4096; u16 = 5713920 + (size_t)c*256; }
        else if(chunk < 22608){ int c = chunk-22464; src = vaS + (size_t)c*4096; u16 = 5750784 + (size_t)c*256; }
        else if(chunk < 22752){ int c = chunk-22608; src = vaR + (size_t)c*4096; u16 = 5787648 + (size_t)c*256; }
        else if(chunk < 22824){ int c = chunk-22752; src = vaN + (size_t)c*4096; u16 = 5824512 + (size_t)c*256; }
        else                  { int c = chunk-22824; src = vaF + (size_t)c*4096; u16 = 5842944 + (size_t)c*256; }

        const int4* s4 = (const int4*)src + (size_t)threadIdx.x*4;
        int4 v0 = s4[0], v1 = s4[1], v2 = s4[2], v3 = s4[3];
        unsigned m =
            ((unsigned)(v0.x!=0)    ) | ((unsigned)(v0.y!=0)<<1 ) | ((unsigned)(v0.z!=0)<<2 ) | ((unsigned)(v0.w!=0)<<3 ) |
            ((unsigned)(v1.x!=0)<<4 ) | ((unsigned)(v1.y!=0)<<5 ) | ((unsigned)(v1.z!=0)<<6 ) | ((unsigned)(v1.w!=0)<<7 ) |
            ((unsigned)(v2.x!=0)<<8 ) | ((unsigned)(v2.y!=0)<<9 ) | ((unsigned)(v2.z!=0)<<10) | ((unsigned)(v2.w!=0)<<11) |
            ((unsigned)(v3.x!=0)<<12) | ((unsigned)(v3.y!=0)<<13) | ((unsigned)(v3.z!=0)<<14) | ((unsigned)(v3.w!=0)<<15);
        bits[u16 + threadIdx.x] = (unsigned short)m;
    }
}

// ---- masked categorical: lp at argmax, argmax (first max), entropy over valid ----
template<int N>
__device__ __forceinline__ void mcat(const float* x, unsigned mask, float& lp, int& a, float& en){
    float ml[N];
    #pragma unroll
    for(int i=0;i<N;i++) ml[i] = ((mask >> i) & 1u) ? x[i] : -1e9f;
    float m = ml[0]; int am = 0;
    #pragma unroll
    for(int i=1;i<N;i++) if(ml[i] > m){ m = ml[i]; am = i; }
    float S = 0.f, T = 0.f;
    #pragma unroll
    for(int i=0;i<N;i++){
        float d = ml[i] - m;
        float e = expf(d);         // invalid entries: exp(-1e9-m) == 0 exactly
        S += e; T += e * d;
    }
    float lS = logf(S);
    lp = -lS;                      // ml[argmax] == m  =>  lp = m - (m + log S)
    a  = am;
    en = lS - T / S;               // == -sum_valid p*lp  (exact when >=1 valid; unused otherwise)
}

// ---------------- Kernel 4: heads fused with bit-plane mask reduction ----------------
// bits byte offsets: bT=0 bM=9216000 bP=9584640 bD=11427840 bS=11501568
//   bR=11575296 bN=11649024 bF=11685888 ; plane byte stride = HW/8 = 1152
__global__ __launch_bounds__(256) void k_heads(
    const float* __restrict__ mf, const float* __restrict__ uf, const float* __restrict__ ff,
    const int* __restrict__ loc,
    const unsigned char* __restrict__ B,
    const float* Wc, const float* bc, const float* Wf, const float* bf,
    const float* Wt, const float* bt, const float* Wmd, const float* bmd,
    const float* Wtd, const float* btd, const float* Wtr, const float* btr,
    const float* Wta, const float* bta, const float* Wpr, const float* bpr,
    const float* Wpa, const float* bpa, const float* Wra, const float* bra,
    const float* Wdr, const float* bdr,
    const float* __restrict__ df,
    float* __restrict__ crm, float* __restrict__ lpm, float* __restrict__ enm,
    int* __restrict__ idx, float* __restrict__ out)
{
    __shared__ float sw[336];
    {
        int t = threadIdx.x;
        #define CPW(off, src, n) for(int i=t;i<(n);i+=256) sw[(off)+i]=(src)[i];
        CPW(0,Wc,5)    CPW(5,bc,1)    CPW(6,Wf,24)   CPW(30,bf,4)
        CPW(34,Wt,35)  CPW(69,bt,7)   CPW(76,Wmd,20) CPW(96,bmd,5)
        CPW(101,Wtd,20) CPW(121,btd,5) CPW(126,Wtr,20) CPW(146,btr,5)
        CPW(151,Wta,40) CPW(191,bta,10) CPW(201,Wpr,20) CPW(221,bpr,5)
        CPW(226,Wpa,40) CPW(266,bpa,10) CPW(276,Wra,40) CPW(316,bra,10)
        CPW(326,Wdr,8)  CPW(334,bdr,2)
        #undef CPW
    }
    __syncthreads();

    int n = blockIdx.x * 256 + threadIdx.x;        // n < NB*HW
    int b = n / HW, p = n % HW;
    size_t q = (size_t)b*HW + p;
    int p8 = p >> 3;
    int j  = p & 7;

    // ---- rebuild masks from bit planes (L2-resident; 8 threads broadcast per byte) ----
    unsigned tv = 0;
    {
        const unsigned char* Tb = B + (size_t)b*250*1152 + p8;
        #pragma unroll 5
        for(int g=0; g<25; g++){
            unsigned a0 = Tb[(size_t)(g*10+0)*1152] | Tb[(size_t)(g*10+1)*1152];
            unsigned a1 = Tb[(size_t)(g*10+2)*1152] | Tb[(size_t)(g*10+3)*1152];
            unsigned a2 = Tb[(size_t)(g*10+4)*1152] | Tb[(size_t)(g*10+5)*1152];
            unsigned a3 = Tb[(size_t)(g*10+6)*1152] | Tb[(size_t)(g*10+7)*1152];
            unsigned a4 = Tb[(size_t)(g*10+8)*1152] | Tb[(size_t)(g*10+9)*1152];
            unsigned acc = (a0|a1) | (a2|a3) | a4;
            tv |= ((acc>>j)&1u) << g;
        }
    }
    unsigned mvm = 0, pkm = 0, digm = 0, sd1, rc1, dn1, fam = 0;
    {
        const unsigned char* Mb = B + 9216000 + (size_t)b*10*1152 + p8;
        #pragma unroll
        for(int d=0; d<5; d++){
            unsigned acc = Mb[(size_t)(2*d)*1152] | Mb[(size_t)(2*d+1)*1152];
            mvm |= ((acc>>j)&1u) << d;
        }
        const unsigned char* Pb = B + 9584640 + (size_t)b*50*1152 + p8;
        #pragma unroll 5
        for(int r=0; r<5; r++){
            unsigned a0 = Pb[(size_t)(r*10+0)*1152] | Pb[(size_t)(r*10+1)*1152];
            unsigned a1 = Pb[(size_t)(r*10+2)*1152] | Pb[(size_t)(r*10+3)*1152];
            unsigned a2 = Pb[(size_t)(r*10+4)*1152] | Pb[(size_t)(r*10+5)*1152];
            unsigned a3 = Pb[(size_t)(r*10+6)*1152] | Pb[(size_t)(r*10+7)*1152];
            unsigned a4 = Pb[(size_t)(r*10+8)*1152] | Pb[(size_t)(r*10+9)*1152];
            unsigned acc = (a0|a1) | (a2|a3) | a4;
            pkm |= ((acc>>j)&1u) << r;
        }
        const unsigned char* Db = B + 11427840 + (size_t)b*2*1152 + p8;
        digm = ((Db[0]>>j)&1u) | (((Db[1152]>>j)&1u)<<1);
        const unsigned char* Sb = B + 11501568 + (size_t)b*2*1152 + p8;
        sd1 = (((unsigned)(Sb[0]|Sb[1152]))>>j)&1u;
        const unsigned char* Rb = B + 11575296 + (size_t)b*2*1152 + p8;
        rc1 = (((unsigned)(Rb[0]|Rb[1152]))>>j)&1u;
        dn1 = ((unsigned)(B[11649024 + (size_t)b*1152 + p8])>>j)&1u;
        const unsigned char* Fb = B + 11685888 + (size_t)b*4*1152 + p8;
        #pragma unroll
        for(int c=0; c<4; c++) fam |= (((unsigned)Fb[(size_t)c*1152]>>j)&1u) << c;
    }

    unsigned uat = (mvm ? 1u:0u) | ((tv ? 1u:0u)<<1) | ((pkm ? 1u:0u)<<2) | ((digm ? 1u:0u)<<3)
                 | (sd1<<4) | (rc1<<5) | (dn1<<6);
    bool um = (uat != 0);

    // features
    float vf5[5];
    vf5[0] = mf[((size_t)b*2+0)*HW + p];
    vf5[1] = mf[((size_t)b*2+1)*HW + p];
    vf5[2] = uf[((size_t)b*3+0)*HW + p];
    vf5[3] = uf[((size_t)b*3+1)*HW + p];
    vf5[4] = uf[((size_t)b*3+2)*HW + p];
    float d4[4];
    #pragma unroll
    for(int o=0;o<4;o++) d4[o] = df[((size_t)b*4+o)*HW + p];
    float f6[6];
    #pragma unroll
    for(int jj=0;jj<6;jj++) f6[jj] = ff[((size_t)b*6+jj)*HW + p];

    // critic
    float critic = sw[5];
    #pragma unroll
    for(int c=0;c<5;c++) critic += sw[c] * vf5[c];

    // factory masked argmax
    int fact = 0; float fb = -3e38f;
    #pragma unroll
    for(int jj=0;jj<4;jj++){
        float lg = sw[30+jj];
        #pragma unroll
        for(int c=0;c<6;c++) lg += sw[6 + jj*6 + c] * f6[c];
        float mlv = ((fam >> jj) & 1u) ? lg : -1e9f;
        if(mlv > fb){ fb = mlv; fact = jj; }
    }

    // act-type head
    float tl[7];
    #pragma unroll
    for(int i=0;i<7;i++){
        float s = sw[69+i];
        #pragma unroll
        for(int c=0;c<5;c++) s += sw[34 + i*5 + c] * vf5[c];
        tl[i] = s;
    }
    float t_lp, t_en; int tt;
    mcat<7>(tl, uat, t_lp, tt, t_en);

    float hl[10];

    #pragma unroll
    for(int i=0;i<5;i++){ float s = sw[96+i];
        #pragma unroll
        for(int c=0;c<4;c++) s += sw[76 + i*4 + c] * d4[c]; hl[i]=s; }
    float lpmv, enmv; int mvdir; mcat<5>(hl, mvm, lpmv, mvdir, enmv);

    #pragma unroll
    for(int i=0;i<5;i++){ float s = sw[121+i];
        #pragma unroll
        for(int c=0;c<4;c++) s += sw[101 + i*4 + c] * d4[c]; hl[i]=s; }
    unsigned trd = 0;
    #pragma unroll
    for(int d=0; d<5; d++) trd |= (unsigned)(((tv >> (5*d)) & 31u) != 0) << d;
    float lptd, entd; int trdir; mcat<5>(hl, trd, lptd, trdir, entd);

    #pragma unroll
    for(int i=0;i<5;i++){ float s = sw[146+i];
        #pragma unroll
        for(int c=0;c<4;c++) s += sw[126 + i*4 + c] * d4[c]; hl[i]=s; }
    float lptr, entr; int trres; mcat<5>(hl, (tv >> (trdir*5)) & 31u, lptr, trres, entr);

    #pragma unroll
    for(int i=0;i<10;i++){ float s = sw[191+i];
        #pragma unroll
        for(int c=0;c<4;c++) s += sw[151 + i*4 + c] * d4[c]; hl[i]=s; }
    float lpta, enta; int tramt; mcat<10>(hl, 0x3FFu, lpta, tramt, enta);

    #pragma unroll
    for(int i=0;i<5;i++){ float s = sw[221+i];
        #pragma unroll
        for(int c=0;c<4;c++) s += sw[201 + i*4 + c] * d4[c]; hl[i]=s; }
    float lppr, enpr; int pkres; mcat<5>(hl, pkm, lppr, pkres, enpr);

    #pragma unroll
    for(int i=0;i<10;i++){ float s = sw[266+i];
        #pragma unroll
        for(int c=0;c<4;c++) s += sw[226 + i*4 + c] * d4[c]; hl[i]=s; }
    float lppa, enpa; int pkamt; mcat<10>(hl, 0x3FFu, lppa, pkamt, enpa);

    #pragma unroll
    for(int i=0;i<10;i++){ float s = sw[316+i];
        #pragma unroll
        for(int c=0;c<4;c++) s += sw[276 + i*4 + c] * d4[c]; hl[i]=s; }
    float lpra, enra; int rcamt; mcat<10>(hl, 0x3FFu, lpra, rcamt, enra);

    #pragma unroll
    for(int i=0;i<2;i++){ float s = sw[334+i];
        #pragma unroll
        for(int c=0;c<4;c++) s += sw[326 + i*4 + c] * d4[c]; hl[i]=s; }
    float lpdg, endg; int dgrep; mcat<2>(hl, digm, lpdg, dgrep, endg);

    float lps = 0.f, ens = 0.f; int dir = 0, res = 0, amt = 0, rep = 0;
    switch(tt){
        case 0: lps = lpmv;               ens = enmv;               dir = mvdir; break;
        case 1: lps = lptd + lptr + lpta; ens = entd + entr + enta; dir = trdir; res = trres; amt = tramt; break;
        case 2: lps = lppr + lppa;        ens = enpr + enpa;        res = pkres; amt = pkamt; break;
        case 3: lps = lpdg;               ens = endg;               rep = dgrep; break;
        case 5: lps = lpra;               ens = enra;               amt = rcamt; break;
        default: break;
    }
    float tot_lp = t_lp + lps;
    float tot_en = t_en + ens;

    crm[q] = critic;
    lpm[q] = tot_lp;
    enm[q] = tot_en;

    out[96000 + q] = (fam != 0) ? (float)fact : 0.f;
    size_t ub = 390912 + (size_t)b*6*HW + p;
    out[ub + 0*HW] = um ? (float)tt  : 0.f;
    out[ub + 1*HW] = um ? (float)dir : 0.f;
    out[ub + 2*HW] = um ? (float)res : 0.f;
    out[ub + 3*HW] = um ? (float)amt : 0.f;
    out[ub + 4*HW] = um ? (float)rep : 0.f;
    out[ub + 5*HW] = um ? 1.f : 0.f;

    // scatter winner: numpy last-write-wins == max linear position per (b,id)
    if(um){
        int id = loc[((size_t)b*2 + 1)*HW + p] + 10;
        if((unsigned)id < 1000u) atomicMax(&idx[b*1000 + id], p);
    }
}

// ---------------- Kernel 5: resolve [B,1000] scatters ----------------
__global__ __launch_bounds__(256) void k_gather(const int* __restrict__ idx,
                                                const float* __restrict__ crm,
                                                const float* __restrict__ lpm,
                                                const float* __restrict__ enm,
                                                float* __restrict__ out){
    int j = blockIdx.x * 256 + threadIdx.x;
    if(j >= 32000) return;
    int b = j / 1000;
    int pos = idx[j];
    float lp = 0.f, cv = 0.f, en = 0.f;
    if(pos >= 0){
        size_t q = (size_t)b*HW + pos;
        lp = lpm[q]; cv = crm[q]; en = enm[q];
    }
    out[j]          = lp;
    out[32000 + j]  = cv;
    out[64000 + j]  = en;
}

extern "C" void kernel_launch(void* const* d_in, const int* in_sizes, int n_in,
                              void* d_out, int out_size, void* d_ws, size_t ws_size,
                              hipStream_t stream) {
    const float* mf  = (const float*)d_in[1];
    const float* ffp = (const float*)d_in[2];
    const float* ufp = (const float*)d_in[3];
    const int*   loc = (const int*)d_in[4];
    const int* vaM = (const int*)d_in[5];
    const int* vaT = (const int*)d_in[6];
    const int* vaP = (const int*)d_in[7];
    const int* vaD = (const int*)d_in[8];
    const int* vaS = (const int*)d_in[9];
    const int* vaR = (const int*)d_in[10];
    const int* vaN = (const int*)d_in[11];
    const int* vaF = (const int*)d_in[12];
    const float *Wf=(const float*)d_in[13], *bf=(const float*)d_in[14];
    const float *Wc=(const float*)d_in[15], *bc=(const float*)d_in[16];
    const float *Wdw=(const float*)d_in[17], *bdw=(const float*)d_in[18];
    const float *Wt=(const float*)d_in[19], *bt=(const float*)d_in[20];
    const float *Wmd=(const float*)d_in[21], *bmd=(const float*)d_in[22];
    const float *Wtd=(const float*)d_in[23], *btd=(const float*)d_in[24];
    const float *Wtr=(const float*)d_in[25], *btr=(const float*)d_in[26];
    const float *Wta=(const float*)d_in[27], *bta=(const float*)d_in[28];
    const float *Wpr=(const float*)d_in[29], *bpr=(const float*)d_in[30];
    const float *Wpa=(const float*)d_in[31], *bpa=(const float*)d_in[32];
    const float *Wra=(const float*)d_in[33], *bra=(const float*)d_in[34];
    const float *Wdr=(const float*)d_in[35], *bdr=(const float*)d_in[36];

    char* ws = (char*)d_ws;
    float* le  = (float*)(ws + 0);                 // 32*2*9216*4  = 2,359,296
    float* df  = (float*)(ws + 2359296);           // 32*4*9216*4  = 4,718,592
    float* crm = (float*)(ws + 7077888);           // 32*9216*4    = 1,179,648
    float* lpm = (float*)(ws + 8257536);
    float* enm = (float*)(ws + 9437184);
    int*   idx = (int*)(ws + 10616832);            // 32*1000*4    = 128,000
    unsigned* mm = (unsigned*)(ws + 10744832);     // 16 B
    unsigned short* bits = (unsigned short*)(ws + 16777216); // 11,833,344 B

    hipMemsetAsync(mm, 0x00, 8, stream);           // max accumulators -> encoded -inf floor
    hipMemsetAsync((char*)mm + 8, 0xFF, 8, stream);// min accumulators -> encoded +inf ceil
    hipMemsetAsync(idx, 0xFF, 128000, stream);     // scatter winners -> -1

    k_bits<<<dim3(2304), dim3(256), 0, stream>>>(vaT, vaM, vaP, vaD, vaS, vaR, vaN, vaF, bits);
    k_le<<<dim3(2304), dim3(256), 0, stream>>>(mf, le, mm);
    k_dirconv<<<dim3(1152), dim3(256), 0, stream>>>(ufp, le, mm, Wdw, bdw, df);
    k_heads<<<dim3(1152), dim3(256), 0, stream>>>(
        mf, ufp, ffp, loc, (const unsigned char*)bits,
        Wc, bc, Wf, bf, Wt, bt, Wmd, bmd, Wtd, btd, Wtr, btr,
        Wta, bta, Wpr, bpr, Wpa, bpa, Wra, bra, Wdr, bdr,
        df, crm, lpm, enm, idx, (float*)d_out);
    k_gather<<<dim3(125), dim3(256), 0, stream>>>(idx, crm, lpm, enm, (float*)d_out);
}

// Round 9
// 163.460 us; speedup vs baseline: 1.2677x; 1.2608x over previous
//
#include <hip/hip_runtime.h>
#include <hip/hip_bf16.h>

// Problem constants (B=32, H=W=96, D=5, R=5, A=10, K=2, FA=4, T=7)
#define HW 9216
#define NB 32

#define NTL(p) __builtin_nontemporal_load(p)

// ---- float <-> order-preserving unsigned encoding for atomic min/max ----
__device__ inline unsigned fenc(float f){
    unsigned u = __float_as_uint(f);
    return (u & 0x80000000u) ? ~u : (u | 0x80000000u);
}
__device__ inline float fdec(unsigned u){
    return __uint_as_float((u & 0x80000000u) ? (u & 0x7fffffffu) : ~u);
}

// ---------------- Kernel 1: le = avgpool3x3(mf)+mf, global per-channel min/max ----------------
__global__ __launch_bounds__(256) void k_le(const float* __restrict__ mf,
                                            float* __restrict__ le,
                                            unsigned* __restrict__ mm /*[4]: max0,max1,min0,min1*/){
    int n = blockIdx.x * 256 + threadIdx.x;        // n < NB*2*HW
    int p = n % HW;
    int bc = n / HW;
    int c = bc & 1;
    int h = p / 96, w = p % 96;
    const float* plane = mf + (size_t)bc * HW;
    float s = 0.f;
    #pragma unroll
    for(int dy=-1; dy<=1; ++dy){
        int y = h + dy;
        if((unsigned)y < 96u){
            #pragma unroll
            for(int dx=-1; dx<=1; ++dx){
                int x = w + dx;
                if((unsigned)x < 96u) s += plane[y*96 + x];
            }
        }
    }
    float v = s * (1.0f/9.0f) + plane[p];
    le[n] = v;

    float mx = v, mn = v;
    #pragma unroll
    for(int o=32; o; o>>=1){
        mx = fmaxf(mx, __shfl_xor(mx, o));
        mn = fminf(mn, __shfl_xor(mn, o));
    }
    __shared__ float smx[4], smn[4];
    int wv = threadIdx.x >> 6;
    if((threadIdx.x & 63) == 0){ smx[wv] = mx; smn[wv] = mn; }
    __syncthreads();
    if(threadIdx.x == 0){
        for(int i=1;i<4;i++){ mx = fmaxf(mx, smx[i]); mn = fminf(mn, smn[i]); }
        atomicMax(&mm[c],     fenc(mx));
        atomicMin(&mm[2 + c], fenc(mn));
    }
}

// ---------------- Kernel 2: df = LeakyReLU(conv3x3([norm(le), uf], Wd) + bd) ----------------
__global__ __launch_bounds__(256) void k_dirconv(const float* __restrict__ uf,
                                                 const float* __restrict__ le,
                                                 const unsigned* __restrict__ mm,
                                                 const float* __restrict__ Wdw,
                                                 const float* __restrict__ bdw,
                                                 float* __restrict__ df){
    __shared__ float sW[180];
    __shared__ float sb[4];
    for(int i=threadIdx.x; i<180; i+=256) sW[i] = Wdw[i];
    if(threadIdx.x < 4) sb[threadIdx.x] = bdw[threadIdx.x];
    __syncthreads();

    int n = blockIdx.x * 256 + threadIdx.x;        // n < NB*HW
    int b = n / HW, p = n % HW;
    int h = p / 96, w = p % 96;

    float mx0 = fdec(mm[0]), mx1 = fdec(mm[1]);
    float mn0 = fdec(mm[2]), mn1 = fdec(mm[3]);
    float sc0 = 2.f / (mx0 - mn0), sc1 = 2.f / (mx1 - mn1);
    float of0 = -1.f - mn0 * sc0,  of1 = -1.f - mn1 * sc1;

    float acc0 = sb[0], acc1 = sb[1], acc2 = sb[2], acc3 = sb[3];
    #pragma unroll
    for(int i=0;i<5;i++){
        #pragma unroll
        for(int ky=0; ky<3; ky++){
            int y = h + ky - 1;
            if((unsigned)y >= 96u) continue;
            #pragma unroll
            for(int kx=0; kx<3; kx++){
                int x = w + kx - 1;
                if((unsigned)x >= 96u) continue;
                float v;
                if(i < 2) v = le[((size_t)b*2 + i)*HW + y*96 + x] * (i ? sc1 : sc0) + (i ? of1 : of0);
                else      v = uf[((size_t)b*3 + (i-2))*HW + y*96 + x];
                acc0 += v * sW[((0*5+i)*3+ky)*3+kx];
                acc1 += v * sW[((1*5+i)*3+ky)*3+kx];
                acc2 += v * sW[((2*5+i)*3+ky)*3+kx];
                acc3 += v * sW[((3*5+i)*3+ky)*3+kx];
            }
        }
    }
    size_t ob = ((size_t)b*4)*HW + p;
    df[ob + 0*HW] = acc0 > 0.f ? acc0 : 0.01f*acc0;
    df[ob + 1*HW] = acc1 > 0.f ? acc1 : 0.01f*acc1;
    df[ob + 2*HW] = acc2 > 0.f ? acc2 : 0.01f*acc2;
    df[ob + 3*HW] = acc3 > 0.f ? acc3 : 0.01f*acc3;
}

// ---- masked categorical: lp at argmax, argmax (first max), entropy over valid ----
template<int N>
__device__ __forceinline__ void mcat(const float* x, unsigned mask, float& lp, int& a, float& en){
    float ml[N];
    #pragma unroll
    for(int i=0;i<N;i++) ml[i] = ((mask >> i) & 1u) ? x[i] : -1e9f;
    float m = ml[0]; int am = 0;
    #pragma unroll
    for(int i=1;i<N;i++) if(ml[i] > m){ m = ml[i]; am = i; }
    float S = 0.f, T = 0.f;
    #pragma unroll
    for(int i=0;i<N;i++){
        float d = ml[i] - m;
        float e = expf(d);         // invalid entries: exp(-1e9-m) == 0 exactly
        S += e; T += e * d;
    }
    float lS = logf(S);
    lp = -lS;                      // ml[argmax] == m  =>  lp = m - (m + log S)
    a  = am;
    en = lS - T / S;               // == -sum_valid p*lp  (exact when >=1 valid; unused otherwise)
}

// ---------------- Kernel 3: per-position fused heads (non-temporal mask stream) ----------------
__global__ __launch_bounds__(256) void k_main(
    const float* __restrict__ mf, const float* __restrict__ uf, const float* __restrict__ ff,
    const int* __restrict__ loc,
    const int* __restrict__ vaM, const int* __restrict__ vaT, const int* __restrict__ vaP,
    const int* __restrict__ vaD, const int* __restrict__ vaS, const int* __restrict__ vaR,
    const int* __restrict__ vaN, const int* __restrict__ vaF,
    const float* Wc, const float* bc, const float* Wf, const float* bf,
    const float* Wt, const float* bt, const float* Wmd, const float* bmd,
    const float* Wtd, const float* btd, const float* Wtr, const float* btr,
    const float* Wta, const float* bta, const float* Wpr, const float* bpr,
    const float* Wpa, const float* bpa, const float* Wra, const float* bra,
    const float* Wdr, const float* bdr,
    const float* __restrict__ df,
    float* __restrict__ crm, float* __restrict__ lpm, float* __restrict__ enm,
    int* __restrict__ idx, float* __restrict__ out)
{
    // shared weight cache, fixed layout
    __shared__ float sw[336];
    {
        int t = threadIdx.x;
        #define CPW(off, src, n) for(int i=t;i<(n);i+=256) sw[(off)+i]=(src)[i];
        CPW(0,Wc,5)    CPW(5,bc,1)    CPW(6,Wf,24)   CPW(30,bf,4)
        CPW(34,Wt,35)  CPW(69,bt,7)   CPW(76,Wmd,20) CPW(96,bmd,5)
        CPW(101,Wtd,20) CPW(121,btd,5) CPW(126,Wtr,20) CPW(146,btr,5)
        CPW(151,Wta,40) CPW(191,bta,10) CPW(201,Wpr,20) CPW(221,bpr,5)
        CPW(226,Wpa,40) CPW(266,bpa,10) CPW(276,Wra,40) CPW(316,bra,10)
        CPW(326,Wdr,8)  CPW(334,bdr,2)
        #undef CPW
    }
    __syncthreads();

    int n = blockIdx.x * 256 + threadIdx.x;        // n < NB*HW
    int b = n / HW, p = n % HW;

    // ---- mask streaming (nt loads: read-once data, don't cache) ----
    const int* vm = vaM + (size_t)b*10*HW + p;
    unsigned mvm = 0;                               // per-direction any-over-K
    #pragma unroll
    for(int d=0; d<5; d++){
        int a0 = NTL(vm + (size_t)(d*2+0)*HW) | NTL(vm + (size_t)(d*2+1)*HW);
        mvm |= (unsigned)(a0 != 0) << d;
    }
    const int* vt = vaT + (size_t)b*250*HW + p;
    unsigned tv = 0;                                // bit (d*5+r): any-over-A
    #pragma unroll
    for(int d=0; d<5; d++){
        #pragma unroll
        for(int r=0; r<5; r++){
            int acc = 0;
            #pragma unroll
            for(int a=0; a<10; a++) acc |= NTL(vt + (size_t)((d*5+r)*10 + a)*HW);
            tv |= (unsigned)(acc != 0) << (d*5 + r);
        }
    }
    const int* vp = vaP + (size_t)b*50*HW + p;
    unsigned pkm = 0;                               // per-resource any-over-A
    #pragma unroll
    for(int r=0; r<5; r++){
        int acc = 0;
        #pragma unroll
        for(int a=0; a<10; a++) acc |= NTL(vp + (size_t)(r*10 + a)*HW);
        pkm |= (unsigned)(acc != 0) << r;
    }
    const int* vd = vaD + (size_t)b*2*HW + p;
    unsigned digm = (unsigned)(NTL(vd) != 0) | ((unsigned)(NTL(vd + HW) != 0) << 1);
    const int* vs = vaS + (size_t)b*2*HW + p;  int sd_any = NTL(vs) | NTL(vs + HW);
    const int* vr = vaR + (size_t)b*2*HW + p;  int rc_any = NTL(vr) | NTL(vr + HW);
    int dn = NTL(vaN + (size_t)b*HW + p);
    const int* vfp = vaF + (size_t)b*4*HW + p;
    unsigned fam = 0;
    #pragma unroll
    for(int j=0; j<4; j++) fam |= (unsigned)(NTL(vfp + (size_t)j*HW) != 0) << j;

    unsigned uat = (mvm ? 1u:0u) | ((tv ? 1u:0u)<<1) | ((pkm ? 1u:0u)<<2) | ((digm ? 1u:0u)<<3)
                 | ((sd_any ? 1u:0u)<<4) | ((rc_any ? 1u:0u)<<5) | ((dn ? 1u:0u)<<6);
    bool um = (uat != 0);

    // ---- features ----
    float vf5[5];
    vf5[0] = mf[((size_t)b*2+0)*HW + p];
    vf5[1] = mf[((size_t)b*2+1)*HW + p];
    vf5[2] = uf[((size_t)b*3+0)*HW + p];
    vf5[3] = uf[((size_t)b*3+1)*HW + p];
    vf5[4] = uf[((size_t)b*3+2)*HW + p];
    float d4[4];
    #pragma unroll
    for(int o=0;o<4;o++) d4[o] = df[((size_t)b*4+o)*HW + p];
    float f6[6];
    #pragma unroll
    for(int j=0;j<6;j++) f6[j] = ff[((size_t)b*6+j)*HW + p];

    // ---- critic (1x1 over value_feature) ----
    float critic = sw[5];
    #pragma unroll
    for(int c=0;c<5;c++) critic += sw[c] * vf5[c];

    // ---- factory masked argmax ----
    int fact = 0; float fb = -3e38f;
    #pragma unroll
    for(int j=0;j<4;j++){
        float lg = sw[30+j];
        #pragma unroll
        for(int c=0;c<6;c++) lg += sw[6 + j*6 + c] * f6[c];
        float mlv = ((fam >> j) & 1u) ? lg : -1e9f;
        if(mlv > fb){ fb = mlv; fact = j; }
    }

    // ---- unit act-type head ----
    float tl[7];
    #pragma unroll
    for(int i=0;i<7;i++){
        float s = sw[69+i];
        #pragma unroll
        for(int c=0;c<5;c++) s += sw[34 + i*5 + c] * vf5[c];
        tl[i] = s;
    }
    float t_lp, t_en; int tt;
    mcat<7>(tl, uat, t_lp, tt, t_en);

    float hl[10];

    // move direction
    #pragma unroll
    for(int i=0;i<5;i++){ float s = sw[96+i];
        #pragma unroll
        for(int c=0;c<4;c++) s += sw[76 + i*4 + c] * d4[c]; hl[i]=s; }
    float lpmv, enmv; int mvdir; mcat<5>(hl, mvm, lpmv, mvdir, enmv);

    // transfer direction
    #pragma unroll
    for(int i=0;i<5;i++){ float s = sw[121+i];
        #pragma unroll
        for(int c=0;c<4;c++) s += sw[101 + i*4 + c] * d4[c]; hl[i]=s; }
    unsigned trd = 0;
    #pragma unroll
    for(int d=0; d<5; d++) trd |= (unsigned)(((tv >> (5*d)) & 31u) != 0) << d;
    float lptd, entd; int trdir; mcat<5>(hl, trd, lptd, trdir, entd);

    // transfer resource (mask = tv row at selected dir)
    #pragma unroll
    for(int i=0;i<5;i++){ float s = sw[146+i];
        #pragma unroll
        for(int c=0;c<4;c++) s += sw[126 + i*4 + c] * d4[c]; hl[i]=s; }
    float lptr, entr; int trres; mcat<5>(hl, (tv >> (trdir*5)) & 31u, lptr, trres, entr);

    // transfer amount (all valid)
    #pragma unroll
    for(int i=0;i<10;i++){ float s = sw[191+i];
        #pragma unroll
        for(int c=0;c<4;c++) s += sw[151 + i*4 + c] * d4[c]; hl[i]=s; }
    float lpta, enta; int tramt; mcat<10>(hl, 0x3FFu, lpta, tramt, enta);

    // pickup resource
    #pragma unroll
    for(int i=0;i<5;i++){ float s = sw[221+i];
        #pragma unroll
        for(int c=0;c<4;c++) s += sw[201 + i*4 + c] * d4[c]; hl[i]=s; }
    float lppr, enpr; int pkres; mcat<5>(hl, pkm, lppr, pkres, enpr);

    // pickup amount
    #pragma unroll
    for(int i=0;i<10;i++){ float s = sw[266+i];
        #pragma unroll
        for(int c=0;c<4;c++) s += sw[226 + i*4 + c] * d4[c]; hl[i]=s; }
    float lppa, enpa; int pkamt; mcat<10>(hl, 0x3FFu, lppa, pkamt, enpa);

    // recharge amount
    #pragma unroll
    for(int i=0;i<10;i++){ float s = sw[316+i];
        #pragma unroll
        for(int c=0;c<4;c++) s += sw[276 + i*4 + c] * d4[c]; hl[i]=s; }
    float lpra, enra; int rcamt; mcat<10>(hl, 0x3FFu, lpra, rcamt, enra);

    // dig (repeat)
    #pragma unroll
    for(int i=0;i<2;i++){ float s = sw[334+i];
        #pragma unroll
        for(int c=0;c<4;c++) s += sw[326 + i*4 + c] * d4[c]; hl[i]=s; }
    float lpdg, endg; int dgrep; mcat<2>(hl, digm, lpdg, dgrep, endg);

    // ---- combine by selected type ----
    float lps = 0.f, ens = 0.f; int dir = 0, res = 0, amt = 0, rep = 0;
    switch(tt){
        case 0: lps = lpmv;               ens = enmv;               dir = mvdir; break;
        case 1: lps = lptd + lptr + lpta; ens = entd + entr + enta; dir = trdir; res = trres; amt = tramt; break;
        case 2: lps = lppr + lppa;        ens = enpr + enpa;        res = pkres; amt = pkamt; break;
        case 3: lps = lpdg;               ens = endg;               rep = dgrep; break;
        case 5: lps = lpra;               ens = enra;               amt = rcamt; break;
        default: break;
    }
    float tot_lp = t_lp + lps;
    float tot_en = t_en + ens;

    size_t q = (size_t)b*HW + p;
    crm[q] = critic;
    lpm[q] = tot_lp;
    enm[q] = tot_en;

    // ---- direct outputs (f32) ----
    out[96000 + q] = (fam != 0) ? (float)fact : 0.f;
    size_t ub = 390912 + (size_t)b*6*HW + p;
    out[ub + 0*HW] = um ? (float)tt  : 0.f;
    out[ub + 1*HW] = um ? (float)dir : 0.f;
    out[ub + 2*HW] = um ? (float)res : 0.f;
    out[ub + 3*HW] = um ? (float)amt : 0.f;
    out[ub + 4*HW] = um ? (float)rep : 0.f;
    out[ub + 5*HW] = um ? 1.f : 0.f;

    // ---- scatter winner: numpy last-write-wins == max linear position per (b,id) ----
    if(um){
        int id = loc[((size_t)b*2 + 1)*HW + p] + 10;
        if((unsigned)id < 1000u) atomicMax(&idx[b*1000 + id], p);
    }
}

// ---------------- Kernel 4: resolve [B,1000] scatters ----------------
__global__ __launch_bounds__(256) void k_gather(const int* __restrict__ idx,
                                                const float* __restrict__ crm,
                                                const float* __restrict__ lpm,
                                                const float* __restrict__ enm,
                                                float* __restrict__ out){
    int j = blockIdx.x * 256 + threadIdx.x;
    if(j >= 32000) return;
    int b = j / 1000;
    int pos = idx[j];
    float lp = 0.f, cv = 0.f, en = 0.f;
    if(pos >= 0){
        size_t q = (size_t)b*HW + pos;
        lp = lpm[q]; cv = crm[q]; en = enm[q];
    }
    out[j]          = lp;
    out[32000 + j]  = cv;
    out[64000 + j]  = en;
}

extern "C" void kernel_launch(void* const* d_in, const int* in_sizes, int n_in,
                              void* d_out, int out_size, void* d_ws, size_t ws_size,
                              hipStream_t stream) {
    const float* mf  = (const float*)d_in[1];
    const float* ffp = (const float*)d_in[2];
    const float* ufp = (const float*)d_in[3];
    const int*   loc = (const int*)d_in[4];
    const int* vaM = (const int*)d_in[5];
    const int* vaT = (const int*)d_in[6];
    const int* vaP = (const int*)d_in[7];
    const int* vaD = (const int*)d_in[8];
    const int* vaS = (const int*)d_in[9];
    const int* vaR = (const int*)d_in[10];
    const int* vaN = (const int*)d_in[11];
    const int* vaF = (const int*)d_in[12];
    const float *Wf=(const float*)d_in[13], *bf=(const float*)d_in[14];
    const float *Wc=(const float*)d_in[15], *bc=(const float*)d_in[16];
    const float *Wdw=(const float*)d_in[17], *bdw=(const float*)d_in[18];
    const float *Wt=(const float*)d_in[19], *bt=(const float*)d_in[20];
    const float *Wmd=(const float*)d_in[21], *bmd=(const float*)d_in[22];
    const float *Wtd=(const float*)d_in[23], *btd=(const float*)d_in[24];
    const float *Wtr=(const float*)d_in[25], *btr=(const float*)d_in[26];
    const float *Wta=(const float*)d_in[27], *bta=(const float*)d_in[28];
    const float *Wpr=(const float*)d_in[29], *bpr=(const float*)d_in[30];
    const float *Wpa=(const float*)d_in[31], *bpa=(const float*)d_in[32];
    const float *Wra=(const float*)d_in[33], *bra=(const float*)d_in[34];
    const float *Wdr=(const float*)d_in[35], *bdr=(const float*)d_in[36];

    char* ws = (char*)d_ws;
    float* le  = (float*)(ws + 0);                 // 32*2*9216*4  = 2,359,296
    float* df  = (float*)(ws + 2359296);           // 32*4*9216*4  = 4,718,592
    float* crm = (float*)(ws + 7077888);           // 32*9216*4    = 1,179,648
    float* lpm = (float*)(ws + 8257536);
    float* enm = (float*)(ws + 9437184);
    int*   idx = (int*)(ws + 10616832);            // 32*1000*4    = 128,000
    unsigned* mm = (unsigned*)(ws + 10744832);     // 4 words

    hipMemsetAsync(mm, 0x00, 8, stream);           // max accumulators -> encoded -inf floor
    hipMemsetAsync((char*)mm + 8, 0xFF, 8, stream);// min accumulators -> encoded +inf ceil
    hipMemsetAsync(idx, 0xFF, 128000, stream);     // scatter winners -> -1

    k_le<<<dim3(2304), dim3(256), 0, stream>>>(mf, le, mm);
    k_dirconv<<<dim3(1152), dim3(256), 0, stream>>>(ufp, le, mm, Wdw, bdw, df);
    k_main<<<dim3(1152), dim3(256), 0, stream>>>(
        mf, ufp, ffp, loc, vaM, vaT, vaP, vaD, vaS, vaR, vaN, vaF,
        Wc, bc, Wf, bf, Wt, bt, Wmd, bmd, Wtd, btd, Wtr, btr,
        Wta, bta, Wpr, bpr, Wpa, bpa, Wra, bra, Wdr, bdr,
        df, crm, lpm, enm, idx, (float*)d_out);
    k_gather<<<dim3(125), dim3(256), 0, stream>>>(idx, crm, lpm, enm, (float*)d_out);
}